// Round 8
// baseline (177.938 us; speedup 1.0000x reference)
//
#include <hip/hip_runtime.h>
#include <stdint.h>

#define NPROP   128
#define C_ALL   19
#define NCLS    18
#define M_TOTAL 400000
#define NPTS    65536
#define CP      (NCLS * NPROP)
#define PTS_PER_CHUNK 8192
#define NCHUNK  8

typedef float f32x4 __attribute__((ext_vector_type(4)));

struct WS {
    float        spred[CP];
    unsigned int keepA[CP];
    unsigned int pointnum[CP];
    unsigned int dense[(size_t)NPROP * NPTS];   // 32 MB: 18 class bits per (p, pt)
};

// ---- kernel 1: zero dense/pointnum + per-proposal softmax & keep preconditions ----
__global__ void zero_prep_kernel(const float* __restrict__ cls_scores,
                                 const float* __restrict__ scores, WS* ws) {
    const size_t tid = (size_t)blockIdx.x * blockDim.x + threadIdx.x;
    const size_t stride = (size_t)gridDim.x * blockDim.x;
    uint4* d4 = (uint4*)ws->dense;
    const size_t n4 = (size_t)NPROP * NPTS / 4;
    const uint4 z = make_uint4(0u, 0u, 0u, 0u);
    for (size_t j = tid; j < n4; j += stride) d4[j] = z;
    if (tid < CP) ws->pointnum[tid] = 0;
    if (tid < NPROP) {
        const int p = (int)tid;
        float row[C_ALL];
        float mx = -3.4e38f;
        #pragma unroll
        for (int i = 0; i < C_ALL; ++i) {
            row[i] = cls_scores[p * C_ALL + i];
            mx = fmaxf(mx, row[i]);
        }
        float s = 0.0f;
        #pragma unroll
        for (int i = 0; i < C_ALL; ++i) {
            row[i] = __expf(row[i] - mx);
            s += row[i];
        }
        const float inv = 1.0f / s;
        #pragma unroll
        for (int c = 0; c < NCLS; ++c) {
            const float soft = row[c] * inv;
            float sc = scores[p * C_ALL + c];
            sc = fminf(fmaxf(sc, 0.0f), 1.0f);
            const float sp = sc * soft;
            ws->spred[c * NPROP + p] = sp;
            ws->keepA[c * NPROP + p] = (soft > 0.001f && sp > -1.0f) ? 1u : 0u;
        }
    }
}

// ---- kernel 2: one pass over M, atomicOr 18 threshold bits into dense ----
__global__ void scatter_kernel(const float* __restrict__ mask_scores,
                               const int* __restrict__ prop_ids,
                               const int* __restrict__ point_ids,
                               WS* ws) {
    int m = blockIdx.x * blockDim.x + threadIdx.x;
    if (m >= M_TOTAL) return;
    const float* r = mask_scores + (size_t)m * C_ALL;
    unsigned int bits = 0;
    #pragma unroll
    for (int c = 0; c < NCLS; ++c)
        bits |= (unsigned int)(r[c] > -0.5f) << c;
    const size_t addr = ((size_t)prop_ids[m] << 16) | (unsigned int)point_ids[m];
    atomicOr(&ws->dense[addr], bits);
}

// ---- kernel 3: popcount dense -> pointnum[c][p] ----
__global__ __launch_bounds__(256) void count_kernel(WS* ws) {
    __shared__ unsigned int cnt[NCLS];
    const int p = blockIdx.x;
    const int quarter = blockIdx.y;
    const int t = threadIdx.x;
    if (t < NCLS) cnt[t] = 0;
    __syncthreads();
    const uint4* base4 = (const uint4*)(ws->dense + ((size_t)p << 16) +
                                        quarter * (NPTS / 4));
    unsigned int local[NCLS];
    #pragma unroll
    for (int c = 0; c < NCLS; ++c) local[c] = 0;
    #pragma unroll
    for (int j = 0; j < (NPTS / 16) / 256; ++j) {     // 16 iters over quarter
        const uint4 w = base4[j * 256 + t];
        #pragma unroll
        for (int c = 0; c < NCLS; ++c)
            local[c] += ((w.x >> c) & 1u) + ((w.y >> c) & 1u) +
                        ((w.z >> c) & 1u) + ((w.w >> c) & 1u);
    }
    #pragma unroll
    for (int c = 0; c < NCLS; ++c) {
        unsigned int v = local[c];
        #pragma unroll
        for (int off = 32; off; off >>= 1) v += __shfl_down(v, off, 64);
        if ((t & 63) == 0) atomicAdd(&cnt[c], v);
    }
    __syncthreads();
    if (t < NCLS) atomicAdd(&ws->pointnum[t * NPROP + p], cnt[t]);
}

// ---- kernel 4: stage chunk in LDS, emit 18 class rows (NT stores) + small outs ----
__global__ __launch_bounds__(256) void write_kernel(const WS* __restrict__ ws,
                                                    float* __restrict__ out) {
    __shared__ unsigned int lds[PTS_PER_CHUNK];   // 32 KiB
    __shared__ float sk[NCLS];
    const int chunk = blockIdx.x;                 // x = chunk: consecutive blocks
    const int p     = blockIdx.y;                 //   write consecutive 32 KB spans
    const int t     = threadIdx.x;

    const uint4* src4 = (const uint4*)(ws->dense + ((size_t)p << 16) +
                                       chunk * PTS_PER_CHUNK);
    uint4* lds4 = (uint4*)lds;
    #pragma unroll
    for (int j = 0; j < (PTS_PER_CHUNK / 4) / 256; ++j)
        lds4[j * 256 + t] = src4[j * 256 + t];

    if (t < NCLS) {
        const int cp = t * NPROP + p;
        const bool k = (ws->keepA[cp] != 0u) && (ws->pointnum[cp] >= 100u);
        sk[t] = k ? 1.0f : 0.0f;
        if (chunk == 0) {
            float* outCS = out + (size_t)CP * NPTS;
            float* outK  = outCS + CP;
            float* outS  = outK  + CP;
            outCS[cp] = k ? ws->spred[cp] : 0.0f;
            outK[cp]  = k ? 1.0f : 0.0f;
            outS[cp]  = (float)(t + 1);
        }
    }
    __syncthreads();

    #pragma unroll 1
    for (int c = 0; c < NCLS; ++c) {
        const float kf = sk[c];
        f32x4* dst = (f32x4*)(out + (((size_t)(c * NPROP + p)) << 16)) +
                     chunk * (PTS_PER_CHUNK / 4);
        #pragma unroll
        for (int j = 0; j < (PTS_PER_CHUNK / 4) / 256; ++j) {
            const int idx = j * 256 + t;
            const uint4 w = lds4[idx];
            f32x4 v;
            v.x = ((w.x >> c) & 1u) ? kf : 0.0f;
            v.y = ((w.y >> c) & 1u) ? kf : 0.0f;
            v.z = ((w.z >> c) & 1u) ? kf : 0.0f;
            v.w = ((w.w >> c) & 1u) ? kf : 0.0f;
            __builtin_nontemporal_store(v, &dst[idx]);
        }
    }
}

extern "C" void kernel_launch(void* const* d_in, const int* in_sizes, int n_in,
                              void* d_out, int out_size, void* d_ws, size_t ws_size,
                              hipStream_t stream) {
    const float* cls_scores  = (const float*)d_in[0];
    const float* scores      = (const float*)d_in[1];
    const float* mask_scores = (const float*)d_in[2];
    const int*   prop_ids    = (const int*)d_in[3];
    const int*   point_ids   = (const int*)d_in[4];

    WS* ws = (WS*)d_ws;
    float* out = (float*)d_out;

    zero_prep_kernel<<<2048, 256, 0, stream>>>(cls_scores, scores, ws);
    const int blocksM = (M_TOTAL + 255) / 256;
    scatter_kernel<<<blocksM, 256, 0, stream>>>(mask_scores, prop_ids, point_ids, ws);
    count_kernel<<<dim3(NPROP, 4), 256, 0, stream>>>(ws);
    write_kernel<<<dim3(NCHUNK, NPROP), 256, 0, stream>>>(ws, out);
}

// Round 9
// 162.204 us; speedup vs baseline: 1.0970x; 1.0970x over previous
//
#include <hip/hip_runtime.h>
#include <stdint.h>

#define NPROP   128
#define C_ALL   19
#define NCLS    18
#define M_TOTAL 400000
#define NPTS    65536
#define CP      (NCLS * NPROP)
#define PTS_PER_CHUNK 8192
#define NCHUNK  8
#define JITERS  ((PTS_PER_CHUNK / 4) / 256)   // 8 float4/uint4 per thread

typedef float f32x4 __attribute__((ext_vector_type(4)));

struct WS {
    float        spred[CP];
    unsigned int keepA[CP];
    unsigned int pointnum[CP];
    unsigned int dense[(size_t)NPROP * NPTS];   // 32 MB: 18 class bits per (p, pt)
};

// ---- kernel 1: zero dense/pointnum + per-proposal softmax & keep preconditions ----
__global__ void zero_prep_kernel(const float* __restrict__ cls_scores,
                                 const float* __restrict__ scores, WS* ws) {
    const size_t tid = (size_t)blockIdx.x * blockDim.x + threadIdx.x;
    const size_t stride = (size_t)gridDim.x * blockDim.x;
    uint4* d4 = (uint4*)ws->dense;
    const size_t n4 = (size_t)NPROP * NPTS / 4;
    const uint4 z = make_uint4(0u, 0u, 0u, 0u);
    for (size_t j = tid; j < n4; j += stride) d4[j] = z;
    if (tid < CP) ws->pointnum[tid] = 0;
    if (tid < NPROP) {
        const int p = (int)tid;
        float row[C_ALL];
        float mx = -3.4e38f;
        #pragma unroll
        for (int i = 0; i < C_ALL; ++i) {
            row[i] = cls_scores[p * C_ALL + i];
            mx = fmaxf(mx, row[i]);
        }
        float s = 0.0f;
        #pragma unroll
        for (int i = 0; i < C_ALL; ++i) {
            row[i] = __expf(row[i] - mx);
            s += row[i];
        }
        const float inv = 1.0f / s;
        #pragma unroll
        for (int c = 0; c < NCLS; ++c) {
            const float soft = row[c] * inv;
            float sc = scores[p * C_ALL + c];
            sc = fminf(fmaxf(sc, 0.0f), 1.0f);
            const float sp = sc * soft;
            ws->spred[c * NPROP + p] = sp;
            ws->keepA[c * NPROP + p] = (soft > 0.001f && sp > -1.0f) ? 1u : 0u;
        }
    }
}

// ---- kernel 2: one pass over M, atomicOr 18 threshold bits into dense ----
__global__ void scatter_kernel(const float* __restrict__ mask_scores,
                               const int* __restrict__ prop_ids,
                               const int* __restrict__ point_ids,
                               WS* ws) {
    int m = blockIdx.x * blockDim.x + threadIdx.x;
    if (m >= M_TOTAL) return;
    const float* r = mask_scores + (size_t)m * C_ALL;
    unsigned int bits = 0;
    #pragma unroll
    for (int c = 0; c < NCLS; ++c)
        bits |= (unsigned int)(r[c] > -0.5f) << c;
    const size_t addr = ((size_t)prop_ids[m] << 16) | (unsigned int)point_ids[m];
    atomicOr(&ws->dense[addr], bits);
}

// ---- kernel 3: popcount dense -> pointnum[c][p] ----
__global__ __launch_bounds__(256) void count_kernel(WS* ws) {
    __shared__ unsigned int cnt[NCLS];
    const int p = blockIdx.x;
    const int quarter = blockIdx.y;
    const int t = threadIdx.x;
    if (t < NCLS) cnt[t] = 0;
    __syncthreads();
    const uint4* base4 = (const uint4*)(ws->dense + ((size_t)p << 16) +
                                        quarter * (NPTS / 4));
    unsigned int local[NCLS];
    #pragma unroll
    for (int c = 0; c < NCLS; ++c) local[c] = 0;
    #pragma unroll
    for (int j = 0; j < (NPTS / 16) / 256; ++j) {     // 16 iters over quarter
        const uint4 w = base4[j * 256 + t];
        #pragma unroll
        for (int c = 0; c < NCLS; ++c)
            local[c] += ((w.x >> c) & 1u) + ((w.y >> c) & 1u) +
                        ((w.z >> c) & 1u) + ((w.w >> c) & 1u);
    }
    #pragma unroll
    for (int c = 0; c < NCLS; ++c) {
        unsigned int v = local[c];
        #pragma unroll
        for (int off = 32; off; off >>= 1) v += __shfl_down(v, off, 64);
        if ((t & 63) == 0) atomicAdd(&cnt[c], v);
    }
    __syncthreads();
    if (t < NCLS) atomicAdd(&ws->pointnum[t * NPROP + p], cnt[t]);
}

// ---- kernel 4: register-staged fanout — each thread owns 8 dense words,
//      emits them into all 18 class streams; no LDS bulk staging ----
__global__ __launch_bounds__(256) void write_kernel(const WS* __restrict__ ws,
                                                    float* __restrict__ out) {
    __shared__ float sk[NCLS];
    const int chunk = blockIdx.x;                 // consecutive blocks -> consecutive
    const int p     = blockIdx.y;                 //   32 KB spans within each stream
    const int t     = threadIdx.x;

    if (t < NCLS) {
        const int cp = t * NPROP + p;
        const bool k = (ws->keepA[cp] != 0u) && (ws->pointnum[cp] >= 100u);
        sk[t] = k ? 1.0f : 0.0f;
        if (chunk == 0) {
            float* outCS = out + (size_t)CP * NPTS;
            float* outK  = outCS + CP;
            float* outS  = outK  + CP;
            outCS[cp] = k ? ws->spred[cp] : 0.0f;
            outK[cp]  = k ? 1.0f : 0.0f;
            outS[cp]  = (float)(t + 1);
        }
    }

    // load this thread's 8 dense words (uint4 each) into registers
    const uint4* src4 = (const uint4*)(ws->dense + ((size_t)p << 16) +
                                       chunk * PTS_PER_CHUNK);
    uint4 w[JITERS];
    #pragma unroll
    for (int j = 0; j < JITERS; ++j)
        w[j] = src4[j * 256 + t];

    __syncthreads();
    float kf[NCLS];
    #pragma unroll
    for (int c = 0; c < NCLS; ++c) kf[c] = sk[c];

    #pragma unroll 1
    for (int c = 0; c < NCLS; ++c) {
        f32x4* dst = (f32x4*)(out + (((size_t)(c * NPROP + p)) << 16)) +
                     chunk * (PTS_PER_CHUNK / 4);
        #pragma unroll
        for (int j = 0; j < JITERS; ++j) {
            f32x4 v;
            v.x = ((w[j].x >> c) & 1u) ? kf[c] : 0.0f;
            v.y = ((w[j].y >> c) & 1u) ? kf[c] : 0.0f;
            v.z = ((w[j].z >> c) & 1u) ? kf[c] : 0.0f;
            v.w = ((w[j].w >> c) & 1u) ? kf[c] : 0.0f;
            dst[j * 256 + t] = v;
        }
    }
}

extern "C" void kernel_launch(void* const* d_in, const int* in_sizes, int n_in,
                              void* d_out, int out_size, void* d_ws, size_t ws_size,
                              hipStream_t stream) {
    const float* cls_scores  = (const float*)d_in[0];
    const float* scores      = (const float*)d_in[1];
    const float* mask_scores = (const float*)d_in[2];
    const int*   prop_ids    = (const int*)d_in[3];
    const int*   point_ids   = (const int*)d_in[4];

    WS* ws = (WS*)d_ws;
    float* out = (float*)d_out;

    zero_prep_kernel<<<2048, 256, 0, stream>>>(cls_scores, scores, ws);
    const int blocksM = (M_TOTAL + 255) / 256;
    scatter_kernel<<<blocksM, 256, 0, stream>>>(mask_scores, prop_ids, point_ids, ws);
    count_kernel<<<dim3(NPROP, 4), 256, 0, stream>>>(ws);
    write_kernel<<<dim3(NCHUNK, NPROP), 256, 0, stream>>>(ws, out);
}